// Round 7
// baseline (1075.711 us; speedup 1.0000x reference)
//
#include <hip/hip_runtime.h>
#include <cmath>

typedef unsigned int uint32;
typedef _Float16 v2h __attribute__((ext_vector_type(2)));

__device__ __forceinline__ float fast_tanh(float x) {
    // tanh(x) = 1 - 2/(exp(2x)+1); correct saturation for large |x|
    float e = __expf(2.0f * x);
    return 1.0f - 2.0f * __builtin_amdgcn_rcpf(e + 1.0f);
}

__device__ __forceinline__ uint32 pkf(float x, float y) {
    v2h v; v.x = (_Float16)x; v.y = (_Float16)y;
    return __builtin_bit_cast(uint32, v);
}
__device__ __forceinline__ v2h bch(uint32 u) { return __builtin_bit_cast(v2h, u); }

__device__ __forceinline__ float dot2(v2h a, v2h b, float c) {
#if __has_builtin(__builtin_amdgcn_fdot2)
    return __builtin_amdgcn_fdot2(a, b, c, false);   // v_dot2_f32_f16, fp32 accum
#else
    return fmaf((float)a[0], (float)b[0], fmaf((float)a[1], (float)b[1], c));
#endif
}

// DPP-based add step: x += dpp_move(x, CTRL); bound_ctrl=true -> invalid lanes give 0.
template <int CTRL>
__device__ __forceinline__ float dpp_radd(float x) {
    int t = __builtin_amdgcn_update_dpp(0, __builtin_bit_cast(int, x),
                                        CTRL, 0xf, 0xf, true);
    return x + __builtin_bit_cast(float, t);
}
// Full wave64 sum -> lane 63, broadcast via readlane (uniform SGPR).
__device__ __forceinline__ float wave_sum_bcast(float x) {
    x = dpp_radd<0x111>(x);   // row_shr:1
    x = dpp_radd<0x112>(x);   // row_shr:2
    x = dpp_radd<0x114>(x);   // row_shr:4
    x = dpp_radd<0x118>(x);   // row_shr:8
    x = dpp_radd<0x142>(x);   // row_bcast:15
    x = dpp_radd<0x143>(x);   // row_bcast:31
    int s = __builtin_amdgcn_readlane(__builtin_bit_cast(int, x), 63);
    return __builtin_bit_cast(float, s);
}

// One wave (64 lanes) integrates one batch row. Lane owns hidden units 2L,2L+1.
// R4 dataflow (LDS h1 exchange + dot2 layer 2 + fp32 DPP layer 3), but with the
// RK4 stage loop ROLLED (not unrolled) so the hot body fits L1I.
__global__ __launch_bounds__(64, 1) void node_kernel(
    const float* __restrict__ y0,        // [B]
    const float* __restrict__ latent,    // [B,32]
    const int*   __restrict__ length,    // [B]
    const float* __restrict__ dense_cs,  // [B,D]
    const float* __restrict__ W1,        // [128,43]
    const float* __restrict__ b1,        // [128]
    const float* __restrict__ W2,        // [128,128]
    const float* __restrict__ b2,        // [128]
    const float* __restrict__ W3,        // [41,128]
    const float* __restrict__ b3,        // [41]
    float* __restrict__ out,             // [B,T]
    int T, int D)
{
    const int lane = threadIdx.x;        // 0..63
    const int row  = blockIdx.x;
    const int u0 = lane * 2, u1 = u0 + 1;

    __shared__ __align__(16) uint32 s_h1[64];   // 128 h1 values as fp16 pairs
    __shared__ __align__(16) float  s_cs[256];  // this row's concentration series

    // stage dense_cs
    if (D == 256) {
        reinterpret_cast<float4*>(s_cs)[lane] =
            reinterpret_cast<const float4*>(dense_cs + row * D)[lane];
    } else {
        for (int q = lane; q < D; q += 64) s_cs[q] = dense_cs[row * D + q];
    }

    // ---- W2 rows u0,u1 -> packed fp16, pinned in registers ----
    uint32 w2a[64], w2b[64];
    {
        const float2* r0 = reinterpret_cast<const float2*>(W2 + u0 * 128);
        const float2* r1 = reinterpret_cast<const float2*>(W2 + u1 * 128);
#pragma unroll
        for (int k = 0; k < 64; ++k) {
            float2 f0 = r0[k], f1 = r1[k];
            w2a[k] = pkf(f0.x, f0.y);
            w2b[k] = pkf(f1.x, f1.y);
        }
    }
#pragma unroll
    for (int k = 0; k < 64; ++k) {
        asm volatile("" : "+v"(w2a[k]));   // opaque: compiler cannot re-sink the loads
        asm volatile("" : "+v"(w2b[k]));
    }

    // ---- W1 rows (state cols + t + c), layer-1 constants ----
    const float* W1r0 = W1 + u0 * 43;
    const float* W1r1 = W1 + u1 * 43;
    float w1a[11], w1b[11];
#pragma unroll
    for (int d = 0; d < 9; ++d) { w1a[d] = W1r0[d]; w1b[d] = W1r1[d]; }
    w1a[9] = W1r0[41]; w1a[10] = W1r0[42];
    w1b[9] = W1r1[41]; w1b[10] = W1r1[42];

    const float* lat = latent + row * 32;
    float c1a = b1[u0], c1b = b1[u1];
#pragma unroll
    for (int l = 0; l < 32; ++l) {
        float lv = lat[l];
        c1a = fmaf(W1r0[9 + l], lv, c1a);
        c1b = fmaf(W1r1[9 + l], lv, c1b);
    }
    const float b2a = b2[u0], b2b = b2[u1];

    // ---- W3 columns (u0,u1) for 9 live outputs, packed fp16; biases fp32 ----
    uint32 w3p[9]; float b3r[9];
#pragma unroll
    for (int i = 0; i < 9; ++i) {
        w3p[i] = pkf(W3[i * 128 + u0], W3[i * 128 + u1]);
        b3r[i] = b3[i];
        asm volatile("" : "+v"(w3p[i]));
    }
#pragma unroll
    for (int d = 0; d < 11; ++d) {
        asm volatile("" : "+v"(w1a[d]));
        asm volatile("" : "+v"(w1b[d]));
    }

    // ---- RK4 state, redundant (uniform) in every lane ----
    const float y00 = y0[row];
    float Y[9], K[9], Ys[9];
#pragma unroll
    for (int i = 0; i < 9; ++i) { Y[i] = (i == 0) ? y00 : 0.0f; Ys[i] = Y[i]; K[i] = 0.0f; }

    int len = length[row] - 1;
    if (len < 0) len = 0;
    const float tend = (float)len;       // ts = arange
    if (lane == 0) out[row * T] = y00;
    __syncthreads();                     // covers the s_cs staging (single wave: cheap)

    const int nsub = (T - 1) * 2;
#pragma unroll 1
    for (int step = 0; step < nsub; ++step) {
        const float t0 = 0.5f * (float)step;   // exact

        // ---- dead-row fast path: vf == 0 for all remaining time (wave-uniform) ----
        if (t0 > tend) {
            const float yv = Y[0];
            for (int i = (step >> 1) + 1 + lane; i < T; i += 64)
                out[row * T + i] = yv;
            break;
        }

        // ---- concentration at the 3 distinct stage times (shared s=1,2) ----
        float cv0, cv1, cv2;
        {
            float tmp[3];
#pragma unroll
            for (int m = 0; m < 3; ++m) {
                const float tau = t0 + 0.25f * (float)m;
                int ii = (int)tau;
                int idx = ii + ((tau - (float)ii) > 0.0f ? 1 : 0);
                idx = min(max(idx, 1), D - 1);
                float w = tau - (float)(idx - 1);
                w = fminf(fmaxf(w, 0.0f), 1.0f);
                tmp[m] = (1.0f - w) * s_cs[idx - 1] + w * s_cs[idx];
            }
            cv0 = tmp[0]; cv1 = tmp[1]; cv2 = tmp[2];
        }

        // ---- RK4: ROLLED stage loop (small body -> fits L1I) ----
#pragma unroll 1
        for (int s = 0; s < 4; ++s) {
            const float toff = (s == 0) ? 0.0f : ((s == 3) ? 0.5f : 0.25f);  // uniform
            const float tau  = t0 + toff;
            const float c    = (s == 0) ? cv0 : ((s == 3) ? cv2 : cv1);       // uniform

            // ---- layer 1: this lane's two hidden units (registers only) ----
            float pa = fmaf(w1a[9], tau, c1a); pa = fmaf(w1a[10], c, pa);
            float pb = fmaf(w1b[9], tau, c1b); pb = fmaf(w1b[10], c, pb);
#pragma unroll
            for (int d = 0; d < 9; ++d) {
                pa = fmaf(w1a[d], Ys[d], pa);
                pb = fmaf(w1b[d], Ys[d], pb);
            }
            s_h1[lane] = pkf(fast_tanh(pa), fast_tanh(pb));
            // single-wave workgroup: no s_barrier needed, just drain LDS
            asm volatile("s_waitcnt lgkmcnt(0)" ::: "memory");

            // ---- layer 2: 2 rows x 64 fp16-pair dots, fp32 accumulate ----
            const uint4* s4 = reinterpret_cast<const uint4*>(s_h1);
            float a0 = 0.f, a1 = 0.f, a2 = 0.f, a3 = 0.f;
            float a4 = 0.f, a5 = 0.f, a6 = 0.f, a7 = 0.f;
            {
                uint4 hb[8];
#pragma unroll
                for (int q = 0; q < 8; ++q) hb[q] = s4[q];
#pragma unroll
                for (int q = 0; q < 8; ++q) {
                    a0 = dot2(bch(w2a[4 * q + 0]), bch(hb[q].x), a0);
                    a2 = dot2(bch(w2a[4 * q + 1]), bch(hb[q].y), a2);
                    a0 = dot2(bch(w2a[4 * q + 2]), bch(hb[q].z), a0);
                    a2 = dot2(bch(w2a[4 * q + 3]), bch(hb[q].w), a2);
                    a1 = dot2(bch(w2b[4 * q + 0]), bch(hb[q].x), a1);
                    a3 = dot2(bch(w2b[4 * q + 1]), bch(hb[q].y), a3);
                    a1 = dot2(bch(w2b[4 * q + 2]), bch(hb[q].z), a1);
                    a3 = dot2(bch(w2b[4 * q + 3]), bch(hb[q].w), a3);
                }
            }
            {
                uint4 hb[8];
#pragma unroll
                for (int q = 0; q < 8; ++q) hb[q] = s4[8 + q];
#pragma unroll
                for (int q = 0; q < 8; ++q) {
                    a4 = dot2(bch(w2a[32 + 4 * q + 0]), bch(hb[q].x), a4);
                    a6 = dot2(bch(w2a[32 + 4 * q + 1]), bch(hb[q].y), a6);
                    a4 = dot2(bch(w2a[32 + 4 * q + 2]), bch(hb[q].z), a4);
                    a6 = dot2(bch(w2a[32 + 4 * q + 3]), bch(hb[q].w), a6);
                    a5 = dot2(bch(w2b[32 + 4 * q + 0]), bch(hb[q].x), a5);
                    a7 = dot2(bch(w2b[32 + 4 * q + 1]), bch(hb[q].y), a7);
                    a5 = dot2(bch(w2b[32 + 4 * q + 2]), bch(hb[q].z), a5);
                    a7 = dot2(bch(w2b[32 + 4 * q + 3]), bch(hb[q].w), a7);
                }
            }
            const float h2a = fast_tanh((a0 + a2) + (a4 + a6) + b2a);
            const float h2b = fast_tanh((a1 + a3) + (a5 + a7) + b2b);
            const uint32 h2p = pkf(h2a, h2b);

            // ---- layer 3: per-lane contribution + DPP wave reduction (VALU only) ----
            float p[9];
#pragma unroll
            for (int i = 0; i < 9; ++i) p[i] = dot2(bch(w3p[i]), bch(h2p), 0.0f);
#pragma unroll
            for (int i = 0; i < 9; ++i) p[i] = wave_sum_bcast(p[i]);

            // ---- vf finalize + RK4 update (uniform selects / branches) ----
            const float alive = (tau <= tend) ? 1.0f : 0.0f;
            float kk[9];
            kk[0] = alive * (-__cosf(p[0] + b3r[0]));
#pragma unroll
            for (int i = 1; i < 9; ++i) kk[i] = alive * (p[i] + b3r[i]);

            if (s == 0) {                    // uniform branch
#pragma unroll
                for (int i = 0; i < 9; ++i) { K[i] = kk[i]; Ys[i] = fmaf(0.25f, kk[i], Y[i]); }
            } else if (s < 3) {              // s = 1,2
                const float a = (s == 2) ? 0.5f : 0.25f;
#pragma unroll
                for (int i = 0; i < 9; ++i) { K[i] = fmaf(2.0f, kk[i], K[i]); Ys[i] = fmaf(a, kk[i], Y[i]); }
            } else {                          // s = 3: commit
#pragma unroll
                for (int i = 0; i < 9; ++i) {
                    K[i] = K[i] + kk[i];
                    Y[i] = fmaf(1.0f / 12.0f, K[i], Y[i]);  // dt/6 = 0.5/6
                    Ys[i] = Y[i];
                }
                if (lane == 0 && (step & 1)) out[row * T + (step >> 1) + 1] = Y[0];
            }
        }
    }
}

extern "C" void kernel_launch(void* const* d_in, const int* in_sizes, int n_in,
                              void* d_out, int out_size, void* d_ws, size_t ws_size,
                              hipStream_t stream) {
    // setup_inputs order:
    // 0 ts[T] 1 y0[B] 2 latent[B,32] 3 length[B] 4 dense_ts[D] 5 dense_cs[B,D]
    // 6 W1 7 b1 8 W2 9 b2 10 W3 11 b3
    const float* y0       = (const float*)d_in[1];
    const float* latent   = (const float*)d_in[2];
    const int*   length   = (const int*)  d_in[3];
    const float* dense_cs = (const float*)d_in[5];
    const float* W1 = (const float*)d_in[6];
    const float* b1 = (const float*)d_in[7];
    const float* W2 = (const float*)d_in[8];
    const float* b2 = (const float*)d_in[9];
    const float* W3 = (const float*)d_in[10];
    const float* b3 = (const float*)d_in[11];
    float* out = (float*)d_out;

    const int T = in_sizes[0];   // 128
    const int B = in_sizes[1];   // 1024
    const int D = in_sizes[4];   // 256

    node_kernel<<<B, 64, 0, stream>>>(y0, latent, length, dense_cs,
                                      W1, b1, W2, b2, W3, b3, out, T, D);
}